// Round 2
// baseline (225.180 us; speedup 1.0000x reference)
//
#include <hip/hip_runtime.h>
#include <stdint.h>

#define S_LEN 1024
#define DM 1024
#define NH 16
#define DH 64
#define NB 4

typedef unsigned short u16;
typedef __attribute__((ext_vector_type(8))) short short8;
typedef __attribute__((ext_vector_type(4))) float f32x4;
typedef __attribute__((ext_vector_type(4))) unsigned int u32x4;

__device__ __forceinline__ u16 f2bf(float f) {
  union { float f; unsigned int u; } c;
  c.f = f;
  unsigned int u = c.u;
  return (u16)((u + 0x7fffu + ((u >> 16) & 1u)) >> 16);
}

// async global->LDS, 16B per lane. LDS dest must be wave-uniform-base + lane*16.
__device__ __forceinline__ void g2l16(const void* g, void* l) {
  __builtin_amdgcn_global_load_lds(
      (const __attribute__((address_space(1))) unsigned int*)(uintptr_t)g,
      (__attribute__((address_space(3))) unsigned int*)(uint32_t)(uintptr_t)l,
      16, 0, 0);
}

// ---------------------------------------------------------------------------
// Kernel 0: fp32 -> bf16 pre-convert of x, Wq, Wk, Wv, Er into workspace.
// Segment boundaries (elements): x 4194304, W* 1048576 each, Er 65536.
// ---------------------------------------------------------------------------
__global__ __launch_bounds__(256) void cvt_f32_bf16(
    const float* __restrict__ x, const float* __restrict__ Wq,
    const float* __restrict__ Wk, const float* __restrict__ Wv,
    const float* __restrict__ Er, u16* __restrict__ xb,
    u16* __restrict__ Wqb, u16* __restrict__ Wkb, u16* __restrict__ Wvb,
    u16* __restrict__ Erb) {
  const size_t f = ((size_t)blockIdx.x * 256 + threadIdx.x) * 8;
  const float* src;
  u16* dst;
  size_t off;
  if (f < 4194304) { src = x; dst = xb; off = f; }
  else if (f < 5242880) { src = Wq; dst = Wqb; off = f - 4194304; }
  else if (f < 6291456) { src = Wk; dst = Wkb; off = f - 5242880; }
  else if (f < 7340032) { src = Wv; dst = Wvb; off = f - 6291456; }
  else { src = Er; dst = Erb; off = f - 7340032; }
  const float4 a = *(const float4*)(src + off);
  const float4 b = *(const float4*)(src + off + 4);
  u16 o[8] = {f2bf(a.x), f2bf(a.y), f2bf(a.z), f2bf(a.w),
              f2bf(b.x), f2bf(b.y), f2bf(b.z), f2bf(b.w)};
  *(u32x4*)(dst + off) = *(const u32x4*)o;
}

// ---------------------------------------------------------------------------
// Kernel 1: fused QKV projection (bf16 in, bf16 out).
// out[m,n] = sum_k x[m,k]*W[n,k] + b[n]
// z=0 -> Q [B,H,S,dh], z=1 -> K [B,H,S,dh], z=2 -> V transposed [B,H,dh,S]
// 128x128 tile, BK=32, 256 threads (4 waves, 2x2 of 64x64), mfma 16x16x32 bf16
// ---------------------------------------------------------------------------
__global__ __launch_bounds__(256) void qkv_gemm(
    const u16* __restrict__ x,
    const u16* __restrict__ Wq, const float* __restrict__ bq,
    const u16* __restrict__ Wk, const float* __restrict__ bk,
    const u16* __restrict__ Wv, const float* __restrict__ bv,
    u16* __restrict__ Qo, u16* __restrict__ Ko, u16* __restrict__ Vo) {
  __shared__ __attribute__((aligned(16))) u16 Al[128 * 32];
  __shared__ __attribute__((aligned(16))) u16 Bl[128 * 32];

  const int tid = threadIdx.x;
  const int lane = tid & 63;
  const int wave = tid >> 6;
  const int z = blockIdx.z;
  const u16* W = (z == 0) ? Wq : (z == 1) ? Wk : Wv;
  const float* bias = (z == 0) ? bq : (z == 1) ? bk : bv;

  const int m0 = blockIdx.y * 128;
  const int n0 = blockIdx.x * 128;

  f32x4 acc[4][4];
  const f32x4 fzero = {0.f, 0.f, 0.f, 0.f};
#pragma unroll
  for (int i = 0; i < 4; i++)
#pragma unroll
    for (int j = 0; j < 4; j++) acc[i][j] = fzero;

  const int srow = tid >> 2;   // 0..63
  const int schunk = tid & 3;  // 16B chunk within 64B row-slab
  const u16* gA = x + (size_t)(m0 + srow) * DM + schunk * 8;
  const u16* gB = W + (size_t)(n0 + srow) * DM + schunk * 8;

  const int fr = lane & 15;
  const int fq = lane >> 4;
  const int wr = (wave >> 1) * 64;
  const int wc = (wave & 1) * 64;

  for (int k = 0; k < DM; k += 32) {
    g2l16(gA + k, &Al[tid * 8]);
    g2l16(gA + (size_t)64 * DM + k, &Al[2048 + tid * 8]);
    g2l16(gB + k, &Bl[tid * 8]);
    g2l16(gB + (size_t)64 * DM + k, &Bl[2048 + tid * 8]);
    __syncthreads();
    short8 a[4], b[4];
#pragma unroll
    for (int i = 0; i < 4; i++)
      a[i] = *(const short8*)&Al[(wr + i * 16 + fr) * 32 + fq * 8];
#pragma unroll
    for (int j = 0; j < 4; j++)
      b[j] = *(const short8*)&Bl[(wc + j * 16 + fr) * 32 + fq * 8];
#pragma unroll
    for (int i = 0; i < 4; i++)
#pragma unroll
      for (int j = 0; j < 4; j++)
        acc[i][j] =
            __builtin_amdgcn_mfma_f32_16x16x32_bf16(a[i], b[j], acc[i][j], 0, 0, 0);
    __syncthreads();
  }

  // epilogue: C/D layout col=lane&15, row=quad*4+reg
#pragma unroll
  for (int j = 0; j < 4; j++) {
    const int n = n0 + wc + j * 16 + fr;
    const float bsv = bias[n];
    const int h = n >> 6, d = n & (DH - 1);
#pragma unroll
    for (int i = 0; i < 4; i++) {
#pragma unroll
      for (int r = 0; r < 4; r++) {
        const int m = m0 + wr + i * 16 + fq * 4 + r;
        const int bb = m >> 10, s = m & (S_LEN - 1);
        const u16 o = f2bf(acc[i][j][r] + bsv);
        if (z == 2)
          Vo[((size_t)(bb * NH + h) * DH + d) * S_LEN + s] = o;  // V^T
        else if (z == 1)
          Ko[((size_t)(bb * NH + h) * S_LEN + s) * DH + d] = o;
        else
          Qo[((size_t)(bb * NH + h) * S_LEN + s) * DH + d] = o;
      }
    }
  }
}

// ---------------------------------------------------------------------------
// Kernel 2: causal flash attention with relative-position (skew) bias.
// logits[i,j] = (q_i.k_j + q_i.Er[S-1-(i-j)]) / 8,  causal softmax,  O = P V.
// Block: one (b,h, 64-row q-tile); 256 threads, wave w owns rows w*16..+16.
// Output written fp32 [B,S,D].
// ---------------------------------------------------------------------------
__global__ __launch_bounds__(256) void attn(
    const u16* __restrict__ Q, const u16* __restrict__ K,
    const u16* __restrict__ Vt, const u16* __restrict__ Er,
    float* __restrict__ out) {
  // LDS: QEl doubles as Q-tile (first) then Er band; scratch doubles as
  // per-wave QEr gather buffer (fp32 16x80) then P tile (bf16 16x72).
  __shared__ __attribute__((aligned(16))) u16 QEl[128 * 72];
  __shared__ __attribute__((aligned(16))) u16 Kl[64 * 72];
  __shared__ __attribute__((aligned(16))) u16 Vl[64 * 72];
  __shared__ __attribute__((aligned(16))) char scratch[4][5120];

  const int tid = threadIdx.x;
  const int lane = tid & 63;
  const int wave = tid >> 6;
  const int bh = blockIdx.y;
  const int b = bh >> 4, h = bh & (NH - 1);
  const int i0 = (int)(gridDim.x - 1 - blockIdx.x) * 64;  // heavy blocks first

  const u16* Qb = Q + (size_t)bh * S_LEN * DH;
  const u16* Kb = K + (size_t)bh * S_LEN * DH;
  const u16* Vb = Vt + (size_t)bh * DH * S_LEN;

  float* Gw = (float*)&scratch[wave][0];  // [16][80] fp32
  u16* Pw = (u16*)&scratch[wave][0];      // [16][72] bf16

  const int sr = tid >> 3;       // 0..31
  const int sc = (tid & 7) * 8;  // element chunk

  // stage Q tile (rows i0..i0+63) into QEl rows 0..63
  *(u32x4*)&QEl[sr * 72 + sc] = *(const u32x4*)&Qb[(i0 + sr) * DH + sc];
  *(u32x4*)&QEl[(sr + 32) * 72 + sc] = *(const u32x4*)&Qb[(i0 + sr + 32) * DH + sc];
  __syncthreads();

  const int fr = lane & 15;
  const int fq = lane >> 4;
  // hoist Q A-fragments (wave's 16 rows, k=0..31 and 32..63)
  short8 aq0 = *(const short8*)&QEl[(wave * 16 + fr) * 72 + fq * 8];
  short8 aq1 = *(const short8*)&QEl[(wave * 16 + fr) * 72 + 32 + fq * 8];
  __syncthreads();  // everyone hoisted before QEl is reused as Er band

  float mrow[4], lrow[4];
  f32x4 accO[4];
  const f32x4 fzero = {0.f, 0.f, 0.f, 0.f};
#pragma unroll
  for (int r = 0; r < 4; r++) { mrow[r] = -3.0e38f; lrow[r] = 0.f; }
#pragma unroll
  for (int t = 0; t < 4; t++) accO[t] = fzero;

  for (int j0 = 0; j0 <= i0; j0 += 64) {
    // ---- stage K rows j0..j0+63, V^T rows d=0..63 cols j0.., Er band 128 rows
    *(u32x4*)&Kl[sr * 72 + sc] = *(const u32x4*)&Kb[(j0 + sr) * DH + sc];
    *(u32x4*)&Kl[(sr + 32) * 72 + sc] = *(const u32x4*)&Kb[(j0 + sr + 32) * DH + sc];
    *(u32x4*)&Vl[sr * 72 + sc] = *(const u32x4*)&Vb[sr * S_LEN + j0 + sc];
    *(u32x4*)&Vl[(sr + 32) * 72 + sc] =
        *(const u32x4*)&Vb[(sr + 32) * S_LEN + j0 + sc];
    const int E0 = S_LEN - 64 - i0 + j0;  // >= 0 always
#pragma unroll
    for (int qq = 0; qq < 4; qq++) {
      const int rr = sr + 32 * qq;
      int e = E0 + rr;
      e = (e > S_LEN - 1) ? (S_LEN - 1) : e;  // OOB rows are masked anyway
      *(u32x4*)&QEl[rr * 72 + sc] = *(const u32x4*)&Er[e * DH + sc];
    }
    __syncthreads();

    // ---- S = Q K^T  (4 col sub-tiles of 16)
    f32x4 sfr[4];
#pragma unroll
    for (int t = 0; t < 4; t++) {
      short8 b0 = *(const short8*)&Kl[(t * 16 + fr) * 72 + fq * 8];
      short8 b1 = *(const short8*)&Kl[(t * 16 + fr) * 72 + 32 + fq * 8];
      f32x4 zz = fzero;
      zz = __builtin_amdgcn_mfma_f32_16x16x32_bf16(aq0, b0, zz, 0, 0, 0);
      zz = __builtin_amdgcn_mfma_f32_16x16x32_bf16(aq1, b1, zz, 0, 0, 0);
      sfr[t] = zz;
    }

    // ---- banded QEr: wave band base in El = 48-16w; 5 frags of 16 cols -> LDS
#pragma unroll
    for (int f = 0; f < 5; f++) {
      const int er = 48 - wave * 16 + f * 16 + fr;  // 0..127
      short8 b0 = *(const short8*)&QEl[er * 72 + fq * 8];
      short8 b1 = *(const short8*)&QEl[er * 72 + 32 + fq * 8];
      f32x4 zz = fzero;
      zz = __builtin_amdgcn_mfma_f32_16x16x32_bf16(aq0, b0, zz, 0, 0, 0);
      zz = __builtin_amdgcn_mfma_f32_16x16x32_bf16(aq1, b1, zz, 0, 0, 0);
#pragma unroll
      for (int r = 0; r < 4; r++)
        Gw[(fq * 4 + r) * 80 + f * 16 + fr] = zz[r];
    }
    __builtin_amdgcn_s_waitcnt(0xC07F);  // lgkmcnt(0): Gw writes visible

    // ---- logits: rel gather (skew) + scale + causal mask
    float p[4][4];
#pragma unroll
    for (int t = 0; t < 4; t++) {
#pragma unroll
      for (int r = 0; r < 4; r++) {
        const int row = fq * 4 + r;
        const float rel = Gw[row * 80 + 15 + t * 16 + fr - row];
        float sv = (sfr[t][r] + rel) * 0.125f;
        const int jj = j0 + t * 16 + fr;
        const int ii = i0 + wave * 16 + row;
        if (jj > ii) sv = -3.0e38f;
        p[t][r] = sv;
      }
    }

    // ---- online softmax (rows live in 16-lane groups)
#pragma unroll
    for (int r = 0; r < 4; r++) {
      float rm = fmaxf(fmaxf(p[0][r], p[1][r]), fmaxf(p[2][r], p[3][r]));
#pragma unroll
      for (int off = 1; off < 16; off <<= 1) rm = fmaxf(rm, __shfl_xor(rm, off));
      const float mnew = fmaxf(mrow[r], rm);
      const float alpha = __expf(mrow[r] - mnew);
      mrow[r] = mnew;
      float rs = 0.f;
#pragma unroll
      for (int t = 0; t < 4; t++) {
        const float e = __expf(p[t][r] - mnew);
        p[t][r] = e;
        rs += e;
      }
#pragma unroll
      for (int off = 1; off < 16; off <<= 1) rs += __shfl_xor(rs, off);
      lrow[r] = lrow[r] * alpha + rs;
#pragma unroll
      for (int t = 0; t < 4; t++) accO[t][r] *= alpha;
    }

    // ---- P -> LDS (C-layout to A-layout round trip), bf16
#pragma unroll
    for (int t = 0; t < 4; t++)
#pragma unroll
      for (int r = 0; r < 4; r++)
        Pw[(fq * 4 + r) * 72 + t * 16 + fr] = f2bf(p[t][r]);
    __builtin_amdgcn_s_waitcnt(0xC07F);  // lgkmcnt(0): Pw writes visible

    short8 ap0 = *(const short8*)&Pw[fr * 72 + fq * 8];
    short8 ap1 = *(const short8*)&Pw[fr * 72 + 32 + fq * 8];
#pragma unroll
    for (int t = 0; t < 4; t++) {
      short8 b0 = *(const short8*)&Vl[(t * 16 + fr) * 72 + fq * 8];
      short8 b1 = *(const short8*)&Vl[(t * 16 + fr) * 72 + 32 + fq * 8];
      accO[t] = __builtin_amdgcn_mfma_f32_16x16x32_bf16(ap0, b0, accO[t], 0, 0, 0);
      accO[t] = __builtin_amdgcn_mfma_f32_16x16x32_bf16(ap1, b1, accO[t], 0, 0, 0);
    }
    __syncthreads();  // before next tile's staging overwrites Kl/Vl/QEl
  }

  // ---- epilogue: O / l, write [B,S,D] fp32
#pragma unroll
  for (int r = 0; r < 4; r++) {
    const float inv = 1.f / lrow[r];
    const int s = i0 + wave * 16 + fq * 4 + r;
#pragma unroll
    for (int t = 0; t < 4; t++) {
      const int d = t * 16 + fr;
      out[((size_t)b * S_LEN + s) * DM + h * DH + d] = accO[t][r] * inv;
    }
  }
}

extern "C" void kernel_launch(void* const* d_in, const int* in_sizes, int n_in,
                              void* d_out, int out_size, void* d_ws, size_t ws_size,
                              hipStream_t stream) {
  const float* x = (const float*)d_in[0];
  const float* Wq = (const float*)d_in[1];
  const float* bq = (const float*)d_in[2];
  const float* Wk = (const float*)d_in[3];
  const float* bk = (const float*)d_in[4];
  const float* Wv = (const float*)d_in[5];
  const float* bv = (const float*)d_in[6];
  const float* Er = (const float*)d_in[7];
  float* out = (float*)d_out;

  const size_t per = (size_t)NB * NH * S_LEN * DH;  // 4M elems
  u16* Qw = (u16*)d_ws;
  u16* Kw = Qw + per;
  u16* Vw = Kw + per;
  u16* xb = Vw + per;
  u16* Wqb = xb + per;
  u16* Wkb = Wqb + (size_t)DM * DM;
  u16* Wvb = Wkb + (size_t)DM * DM;
  u16* Erb = Wvb + (size_t)DM * DM;

  // total convert: 4M + 3*1M + 64K elems = 7405568 -> /8/256 = 3616 blocks
  cvt_f32_bf16<<<3616, 256, 0, stream>>>(x, Wq, Wk, Wv, Er, xb, Wqb, Wkb, Wvb,
                                         Erb);
  dim3 g1(DM / 128, (NB * S_LEN) / 128, 3);
  qkv_gemm<<<g1, dim3(256), 0, stream>>>(xb, Wqb, bq, Wkb, bk, Wvb, bv, Qw, Kw,
                                         Vw);
  dim3 g2(S_LEN / 64, NB * NH);
  attn<<<g2, dim3(256), 0, stream>>>(Qw, Kw, Vw, Erb, out);
}

// Round 3
// 179.464 us; speedup vs baseline: 1.2547x; 1.2547x over previous
//
#include <hip/hip_runtime.h>
#include <stdint.h>

#define S_LEN 1024
#define DM 1024
#define NH 16
#define DH 64
#define NB 4

typedef unsigned short u16;
typedef __attribute__((ext_vector_type(8))) short short8;
typedef __attribute__((ext_vector_type(4))) float f32x4;
typedef __attribute__((ext_vector_type(4))) unsigned int u32x4;

__device__ __forceinline__ u16 f2bf(float f) {
  union { float f; unsigned int u; } c;
  c.f = f;
  unsigned int u = c.u;
  return (u16)((u + 0x7fffu + ((u >> 16) & 1u)) >> 16);
}

// async global->LDS, 16B per lane. LDS dest must be wave-uniform-base + lane*16.
__device__ __forceinline__ void g2l16(const void* g, void* l) {
  __builtin_amdgcn_global_load_lds(
      (const __attribute__((address_space(1))) unsigned int*)(uintptr_t)g,
      (__attribute__((address_space(3))) unsigned int*)(uint32_t)(uintptr_t)l,
      16, 0, 0);
}

// ---------------------------------------------------------------------------
// Kernel 0: fp32 -> bf16 pre-convert of x, Wq, Wk, Wv, Er into workspace.
// ---------------------------------------------------------------------------
__global__ __launch_bounds__(256) void cvt_f32_bf16(
    const float* __restrict__ x, const float* __restrict__ Wq,
    const float* __restrict__ Wk, const float* __restrict__ Wv,
    const float* __restrict__ Er, u16* __restrict__ xb,
    u16* __restrict__ Wqb, u16* __restrict__ Wkb, u16* __restrict__ Wvb,
    u16* __restrict__ Erb) {
  const size_t f = ((size_t)blockIdx.x * 256 + threadIdx.x) * 8;
  const float* src;
  u16* dst;
  size_t off;
  if (f < 4194304) { src = x; dst = xb; off = f; }
  else if (f < 5242880) { src = Wq; dst = Wqb; off = f - 4194304; }
  else if (f < 6291456) { src = Wk; dst = Wkb; off = f - 5242880; }
  else if (f < 7340032) { src = Wv; dst = Wvb; off = f - 6291456; }
  else { src = Er; dst = Erb; off = f - 7340032; }
  const float4 a = *(const float4*)(src + off);
  const float4 b = *(const float4*)(src + off + 4);
  u16 o[8] = {f2bf(a.x), f2bf(a.y), f2bf(a.z), f2bf(a.w),
              f2bf(b.x), f2bf(b.y), f2bf(b.z), f2bf(b.w)};
  *(u32x4*)(dst + off) = *(const u32x4*)o;
}

// ---------------------------------------------------------------------------
// Kernel 1: fused QKV projection (bf16 in, bf16 out).
// z=0 -> Q [B,H,S,dh], z=1 -> K [B,H,S,dh], z=2 -> V transposed [B,H,dh,S]
// ---------------------------------------------------------------------------
__global__ __launch_bounds__(256) void qkv_gemm(
    const u16* __restrict__ x,
    const u16* __restrict__ Wq, const float* __restrict__ bq,
    const u16* __restrict__ Wk, const float* __restrict__ bk,
    const u16* __restrict__ Wv, const float* __restrict__ bv,
    u16* __restrict__ Qo, u16* __restrict__ Ko, u16* __restrict__ Vo) {
  __shared__ __attribute__((aligned(16))) u16 Al[128 * 32];
  __shared__ __attribute__((aligned(16))) u16 Bl[128 * 32];

  const int tid = threadIdx.x;
  const int lane = tid & 63;
  const int wave = tid >> 6;
  const int z = blockIdx.z;
  const u16* W = (z == 0) ? Wq : (z == 1) ? Wk : Wv;
  const float* bias = (z == 0) ? bq : (z == 1) ? bk : bv;

  const int m0 = blockIdx.y * 128;
  const int n0 = blockIdx.x * 128;

  f32x4 acc[4][4];
  const f32x4 fzero = {0.f, 0.f, 0.f, 0.f};
#pragma unroll
  for (int i = 0; i < 4; i++)
#pragma unroll
    for (int j = 0; j < 4; j++) acc[i][j] = fzero;

  const int srow = tid >> 2;
  const int schunk = tid & 3;
  const u16* gA = x + (size_t)(m0 + srow) * DM + schunk * 8;
  const u16* gB = W + (size_t)(n0 + srow) * DM + schunk * 8;

  const int fr = lane & 15;
  const int fq = lane >> 4;
  const int wr = (wave >> 1) * 64;
  const int wc = (wave & 1) * 64;

  for (int k = 0; k < DM; k += 32) {
    g2l16(gA + k, &Al[tid * 8]);
    g2l16(gA + (size_t)64 * DM + k, &Al[2048 + tid * 8]);
    g2l16(gB + k, &Bl[tid * 8]);
    g2l16(gB + (size_t)64 * DM + k, &Bl[2048 + tid * 8]);
    __syncthreads();
    short8 a[4], b[4];
#pragma unroll
    for (int i = 0; i < 4; i++)
      a[i] = *(const short8*)&Al[(wr + i * 16 + fr) * 32 + fq * 8];
#pragma unroll
    for (int j = 0; j < 4; j++)
      b[j] = *(const short8*)&Bl[(wc + j * 16 + fr) * 32 + fq * 8];
#pragma unroll
    for (int i = 0; i < 4; i++)
#pragma unroll
      for (int j = 0; j < 4; j++)
        acc[i][j] =
            __builtin_amdgcn_mfma_f32_16x16x32_bf16(a[i], b[j], acc[i][j], 0, 0, 0);
    __syncthreads();
  }

#pragma unroll
  for (int j = 0; j < 4; j++) {
    const int n = n0 + wc + j * 16 + fr;
    const float bsv = bias[n];
    const int h = n >> 6, d = n & (DH - 1);
#pragma unroll
    for (int i = 0; i < 4; i++) {
#pragma unroll
      for (int r = 0; r < 4; r++) {
        const int m = m0 + wr + i * 16 + fq * 4 + r;
        const int bb = m >> 10, s = m & (S_LEN - 1);
        const u16 o = f2bf(acc[i][j][r] + bsv);
        if (z == 2)
          Vo[((size_t)(bb * NH + h) * DH + d) * S_LEN + s] = o;  // V^T
        else if (z == 1)
          Ko[((size_t)(bb * NH + h) * S_LEN + s) * DH + d] = o;
        else
          Qo[((size_t)(bb * NH + h) * S_LEN + s) * DH + d] = o;
      }
    }
  }
}

// ---------------------------------------------------------------------------
// Kernel 2: causal flash attention with relative-position (skew) bias.
// Block: (b,h, 128-row q-tile), 512 threads = 8 waves, wave w owns 16 rows.
// j-tiles of 64. Skew gather done in-register via __shfl (ds_bpermute).
// ---------------------------------------------------------------------------
__global__ __launch_bounds__(512, 4) void attn(
    const u16* __restrict__ Q, const u16* __restrict__ K,
    const u16* __restrict__ Vt, const u16* __restrict__ Er,
    float* __restrict__ out) {
  // El: Q-tile (128 rows) during init, then Er band (192 rows) per j-iter.
  __shared__ __attribute__((aligned(16))) u16 El[192 * 72];
  __shared__ __attribute__((aligned(16))) u16 Kl[64 * 72];
  __shared__ __attribute__((aligned(16))) u16 Vl[64 * 72];
  __shared__ __attribute__((aligned(16))) u16 Pl[8 * 16 * 72];

  const int tid = threadIdx.x;
  const int lane = tid & 63;
  const int w = tid >> 6;  // wave 0..7
  const int bh = blockIdx.y;
  const int b = bh >> 4, h = bh & (NH - 1);
  // pair heavy i-tiles with light ones across the 2 scheduling rounds
  const int it = (blockIdx.y < 32) ? (int)blockIdx.x : 7 - (int)blockIdx.x;
  const int i0 = it * 128;

  const u16* Qb = Q + (size_t)bh * S_LEN * DH;
  const u16* Kb = K + (size_t)bh * S_LEN * DH;
  const u16* Vb = Vt + (size_t)bh * DH * S_LEN;
  u16* Pw = Pl + w * 16 * 72;

  const int sr = tid >> 3;       // 0..63
  const int sc = (tid & 7) * 8;  // element chunk

  // stage Q tile (128 rows) into El rows 0..127
  *(u32x4*)&El[sr * 72 + sc] = *(const u32x4*)&Qb[(i0 + sr) * DH + sc];
  *(u32x4*)&El[(sr + 64) * 72 + sc] =
      *(const u32x4*)&Qb[(i0 + sr + 64) * DH + sc];
  __syncthreads();

  const int fr = lane & 15;
  const int fq = lane >> 4;
  short8 aq0 = *(const short8*)&El[(w * 16 + fr) * 72 + fq * 8];
  short8 aq1 = *(const short8*)&El[(w * 16 + fr) * 72 + 32 + fq * 8];
  __syncthreads();  // hoisted before El reused as Er band

  float mrow[4], lrow[4];
  f32x4 accO[4];
  const f32x4 fzero = {0.f, 0.f, 0.f, 0.f};
#pragma unroll
  for (int r = 0; r < 4; r++) { mrow[r] = -3.0e38f; lrow[r] = 0.f; }
#pragma unroll
  for (int t = 0; t < 4; t++) accO[t] = fzero;

  for (int j0 = 0; j0 <= i0 + 64; j0 += 64) {
    // ---- stage K (64x64), V^T (64 d-rows x 64 cols), Er band (192 rows)
    *(u32x4*)&Kl[sr * 72 + sc] = *(const u32x4*)&Kb[(j0 + sr) * DH + sc];
    *(u32x4*)&Vl[sr * 72 + sc] = *(const u32x4*)&Vb[sr * S_LEN + j0 + sc];
    const int E0 = S_LEN - 128 - i0 + j0;  // >= 0
#pragma unroll
    for (int qq = 0; qq < 3; qq++) {
      const int g = sr + 64 * qq;
      int e = E0 + g;
      e = (e > S_LEN - 1) ? (S_LEN - 1) : e;  // OOB rows are masked anyway
      *(u32x4*)&El[g * 72 + sc] = *(const u32x4*)&Er[e * DH + sc];
    }
    __syncthreads();

    if (j0 <= i0 + w * 16 + 15) {  // wave has at least one unmasked element
      // ---- S = Q K^T (4 col sub-tiles of 16)
      f32x4 sfr[4];
#pragma unroll
      for (int t = 0; t < 4; t++) {
        short8 b0 = *(const short8*)&Kl[(t * 16 + fr) * 72 + fq * 8];
        short8 b1 = *(const short8*)&Kl[(t * 16 + fr) * 72 + 32 + fq * 8];
        f32x4 zz = fzero;
        zz = __builtin_amdgcn_mfma_f32_16x16x32_bf16(aq0, b0, zz, 0, 0, 0);
        zz = __builtin_amdgcn_mfma_f32_16x16x32_bf16(aq1, b1, zz, 0, 0, 0);
        sfr[t] = zz;
      }

      // ---- banded QEr: 5 frags, band base for wave w at rows 112-16w
      f32x4 zz[5];
#pragma unroll
      for (int f = 0; f < 5; f++) {
        const int er = 112 - w * 16 + f * 16 + fr;  // 0..191
        short8 b0 = *(const short8*)&El[er * 72 + fq * 8];
        short8 b1 = *(const short8*)&El[er * 72 + 32 + fq * 8];
        f32x4 t0 = fzero;
        t0 = __builtin_amdgcn_mfma_f32_16x16x32_bf16(aq0, b0, t0, 0, 0, 0);
        t0 = __builtin_amdgcn_mfma_f32_16x16x32_bf16(aq1, b1, t0, 0, 0, 0);
        zz[f] = t0;
      }

      // ---- in-register skew gather: rel[t][r] = band col (15-row+fr)+16t
      float p[4][4];
#pragma unroll
      for (int r = 0; r < 4; r++) {
        const int row = fq * 4 + r;
        const int c = 15 - row + fr;            // 0..30
        const int src = (fq << 4) | (c & 15);   // same row-group, lane c&15
        float sh[5];
#pragma unroll
        for (int f = 0; f < 5; f++) sh[f] = __shfl(zz[f][r], src);
#pragma unroll
        for (int t = 0; t < 4; t++) {
          const float rel = (c < 16) ? sh[t] : sh[t + 1];
          float sv = (sfr[t][r] + rel) * 0.125f;
          const int jj = j0 + t * 16 + fr;
          const int ii = i0 + w * 16 + row;
          if (jj > ii) sv = -3.0e38f;
          p[t][r] = sv;
        }
      }

      // ---- online softmax (rows live in 16-lane groups)
#pragma unroll
      for (int r = 0; r < 4; r++) {
        float rm = fmaxf(fmaxf(p[0][r], p[1][r]), fmaxf(p[2][r], p[3][r]));
#pragma unroll
        for (int off = 1; off < 16; off <<= 1)
          rm = fmaxf(rm, __shfl_xor(rm, off));
        const float mnew = fmaxf(mrow[r], rm);
        const float alpha = __expf(mrow[r] - mnew);
        mrow[r] = mnew;
        float rs = 0.f;
#pragma unroll
        for (int t = 0; t < 4; t++) {
          const float e = __expf(p[t][r] - mnew);
          p[t][r] = e;
          rs += e;
        }
#pragma unroll
        for (int off = 1; off < 16; off <<= 1) rs += __shfl_xor(rs, off);
        lrow[r] = lrow[r] * alpha + rs;
#pragma unroll
        for (int t = 0; t < 4; t++) accO[t][r] *= alpha;
      }

      // ---- P -> LDS (C-layout to A-layout round trip), wave-private
#pragma unroll
      for (int t = 0; t < 4; t++)
#pragma unroll
        for (int r = 0; r < 4; r++)
          Pw[(fq * 4 + r) * 72 + t * 16 + fr] = f2bf(p[t][r]);
      __builtin_amdgcn_s_waitcnt(0xC07F);  // lgkmcnt(0): Pw writes visible

      short8 ap0 = *(const short8*)&Pw[fr * 72 + fq * 8];
      short8 ap1 = *(const short8*)&Pw[fr * 72 + 32 + fq * 8];
#pragma unroll
      for (int t = 0; t < 4; t++) {
        short8 b0 = *(const short8*)&Vl[(t * 16 + fr) * 72 + fq * 8];
        short8 b1 = *(const short8*)&Vl[(t * 16 + fr) * 72 + 32 + fq * 8];
        accO[t] =
            __builtin_amdgcn_mfma_f32_16x16x32_bf16(ap0, b0, accO[t], 0, 0, 0);
        accO[t] =
            __builtin_amdgcn_mfma_f32_16x16x32_bf16(ap1, b1, accO[t], 0, 0, 0);
      }
    }
    __syncthreads();  // before next tile's staging overwrites Kl/Vl/El
  }

  // ---- epilogue: O / l, write [B,S,D] fp32
#pragma unroll
  for (int r = 0; r < 4; r++) {
    const float inv = 1.f / lrow[r];
    const int s = i0 + w * 16 + fq * 4 + r;
#pragma unroll
    for (int t = 0; t < 4; t++) {
      const int d = t * 16 + fr;
      out[((size_t)b * S_LEN + s) * DM + h * DH + d] = accO[t][r] * inv;
    }
  }
}

extern "C" void kernel_launch(void* const* d_in, const int* in_sizes, int n_in,
                              void* d_out, int out_size, void* d_ws, size_t ws_size,
                              hipStream_t stream) {
  const float* x = (const float*)d_in[0];
  const float* Wq = (const float*)d_in[1];
  const float* bq = (const float*)d_in[2];
  const float* Wk = (const float*)d_in[3];
  const float* bk = (const float*)d_in[4];
  const float* Wv = (const float*)d_in[5];
  const float* bv = (const float*)d_in[6];
  const float* Er = (const float*)d_in[7];
  float* out = (float*)d_out;

  const size_t per = (size_t)NB * NH * S_LEN * DH;  // 4M elems
  u16* Qw = (u16*)d_ws;
  u16* Kw = Qw + per;
  u16* Vw = Kw + per;
  u16* xb = Vw + per;
  u16* Wqb = xb + per;
  u16* Wkb = Wqb + (size_t)DM * DM;
  u16* Wvb = Wkb + (size_t)DM * DM;
  u16* Erb = Wvb + (size_t)DM * DM;

  cvt_f32_bf16<<<3616, 256, 0, stream>>>(x, Wq, Wk, Wv, Er, xb, Wqb, Wkb, Wvb,
                                         Erb);
  dim3 g1(DM / 128, (NB * S_LEN) / 128, 3);
  qkv_gemm<<<g1, dim3(256), 0, stream>>>(xb, Wqb, bq, Wkb, bk, Wvb, bv, Qw, Kw,
                                         Vw);
  dim3 g2(8, NB * NH);
  attn<<<g2, dim3(512), 0, stream>>>(Qw, Kw, Vw, Erb, out);
}